// Round 6
// baseline (1344.921 us; speedup 1.0000x reference)
//
#include <hip/hip_runtime.h>
#include <cstdint>
#include <cstddef>

#define B_ROWS 65536
#define DMODEL 2048
#define NEXP 64
#define TOPK 8
#define THREADS 128                    // 2 waves; 64 rows per wave
#define ROWS_PER_BLK 128
#define NBLK (B_ROWS / ROWS_PER_BLK)   // 512 blocks = 2 per CU
#define DC 16                          // dds per staged chunk
#define NCH (DMODEL / DC)              // 128
// LDS float layout (union):
//   loop:  x slab: wave w, buf b at w*2112 + b*1056   (8 rg-blocks x 132)
//          W slab: 4224 + b*1088                      (16 dds x 68, shifted)
//   epi:   slab 2*64*68 = 8704, then redF/redP 256
#define XW 2112
#define XB 1056
#define WBASE 4224
#define WB 1088
#define SLAB 68
#define RED (2 * 64 * SLAB)
#define GOFF ((size_t)B_ROWS * NEXP)
#define AUX_OFF (GOFF + (size_t)B_ROWS * TOPK)

__global__ __launch_bounds__(THREADS, 1) void router_main(
    const float* __restrict__ x, const float* __restrict__ W,
    const float* __restrict__ bias, float* __restrict__ out,
    float* __restrict__ ws)
{
  __shared__ __align__(16) float lds[RED + 256];

  const int tid = threadIdx.x;
  const int lane = tid & 63;
  const int w = tid >> 6;
  const int eg = lane & 7;        // expert group (8 experts)
  const int rg = lane >> 3;       // row group (8 rows)
  const size_t row0 = (size_t)blockIdx.x * ROWS_PER_BLK;
  const size_t wrow0 = row0 + (size_t)w * 64;

  float acc[8][8];
#pragma unroll
  for (int r = 0; r < 8; ++r)
#pragma unroll
    for (int e = 0; e < 8; ++e) acc[r][e] = 0.f;

  // ---- staging address precompute (per lane) ----
  // x global: instr i covers rows i*16..i*16+15; lane -> row lane>>2, 16B col lane&3
  const float* xg = x + (wrow0 + (size_t)(lane >> 2)) * DMODEL + (lane & 3) * 4;
  // x LDS write: row = i*16 + (lane>>2) -> rg_w = 2i + (lane>>5), rr = (lane>>2)&7
  const int xw_off = w * XW + (lane >> 5) * 132 + ((lane >> 2) & 7) * 16 + (lane & 3) * 4;
  // W global: instr j: dd = c*16 + w*8 + j*4 + (lane>>4), e4 = lane&15
  const float* wg = W + (size_t)(w * 8 + (lane >> 4)) * NEXP + (lane & 15) * 4;
  // W LDS write: pos = dd_local*68 + e4*4 + (e4>=8 ? 4 : 0)
  const int ww_off = WBASE + (w * 8 + (lane >> 4)) * SLAB + (lane & 15) * 4
                   + (((lane & 15) >= 8) ? 4 : 0);
  // read bases
  const int xrd_off = w * XW + rg * 132;
  const int wrd_off = WBASE + eg * 8 + (eg >> 2) * 4;

  float4 xr0[4], xr1[4], wr0[2], wr1[2];

#define LOADX(c, xr)                                                        \
  do { _Pragma("unroll") for (int i = 0; i < 4; ++i)                        \
    xr[i] = *(const float4*)(xg + (size_t)i * 16 * DMODEL + (c) * DC); } while (0)
#define LOADW(c, wr)                                                        \
  do { _Pragma("unroll") for (int j = 0; j < 2; ++j)                        \
    wr[j] = *(const float4*)(wg + (size_t)(c) * DC * NEXP + j * 4 * NEXP); } while (0)
#define WRITEX(xr, b)                                                       \
  do { _Pragma("unroll") for (int i = 0; i < 4; ++i)                        \
    *(float4*)(lds + xw_off + (b) * XB + i * 264) = xr[i]; } while (0)
#define WRITEW(wr, b)                                                       \
  do { _Pragma("unroll") for (int j = 0; j < 2; ++j)                        \
    *(float4*)(lds + ww_off + (b) * WB + j * 4 * SLAB) = wr[j]; } while (0)

#define COMPUTE(b)                                                          \
  do {                                                                      \
    const float* xrd = lds + xrd_off + (b) * XB;                            \
    const float* wrd = lds + wrd_off + (b) * WB;                            \
    _Pragma("unroll") for (int d4 = 0; d4 < 4; ++d4) {                      \
      float4 xv[8];                                                         \
      _Pragma("unroll") for (int rr = 0; rr < 8; ++rr)                      \
        xv[rr] = *(const float4*)(xrd + rr * 16 + d4 * 4);                  \
      _Pragma("unroll") for (int k = 0; k < 4; ++k) {                       \
        const float* wp = wrd + (d4 * 4 + k) * SLAB;                        \
        float4 wlo = *(const float4*)(wp);                                  \
        float4 whi = *(const float4*)(wp + 4);                              \
        _Pragma("unroll") for (int rr = 0; rr < 8; ++rr) {                  \
          float xs_ = (k == 0) ? xv[rr].x : (k == 1) ? xv[rr].y             \
                     : (k == 2) ? xv[rr].z : xv[rr].w;                      \
          acc[rr][0] = fmaf(xs_, wlo.x, acc[rr][0]);                        \
          acc[rr][1] = fmaf(xs_, wlo.y, acc[rr][1]);                        \
          acc[rr][2] = fmaf(xs_, wlo.z, acc[rr][2]);                        \
          acc[rr][3] = fmaf(xs_, wlo.w, acc[rr][3]);                        \
          acc[rr][4] = fmaf(xs_, whi.x, acc[rr][4]);                        \
          acc[rr][5] = fmaf(xs_, whi.y, acc[rr][5]);                        \
          acc[rr][6] = fmaf(xs_, whi.z, acc[rr][6]);                        \
          acc[rr][7] = fmaf(xs_, whi.w, acc[rr][7]);                        \
        }                                                                   \
      }                                                                     \
    }                                                                       \
  } while (0)

  // prologue: chunk0 -> set0 -> buf0; chunk1 -> set1
  LOADX(0, xr0); LOADW(0, wr0);
  WRITEX(xr0, 0); WRITEW(wr0, 0);
  LOADX(1, xr1); LOADW(1, wr1);
  __syncthreads();

  for (int c2 = 0; c2 < NCH / 2; ++c2) {
    // chunk 2*c2 from buf0
    COMPUTE(0);
    WRITEX(xr1, 1); WRITEW(wr1, 1);           // chunk 2*c2+1 -> buf1
    if (c2 < NCH / 2 - 1) { LOADX(2 * c2 + 2, xr0); LOADW(2 * c2 + 2, wr0); }
    __syncthreads();
    // chunk 2*c2+1 from buf1
    COMPUTE(1);
    if (c2 < NCH / 2 - 1) {
      WRITEX(xr0, 0); WRITEW(wr0, 0);         // chunk 2*c2+2 -> buf0
      LOADX(2 * c2 + 3, xr1); LOADW(2 * c2 + 3, wr1);
    }
    __syncthreads();
  }

  // ---- transpose acc -> slab[row][expert] (wave-private region) ----
  float* slab = lds + w * (64 * SLAB);
#pragma unroll
  for (int rr = 0; rr < 8; ++rr) {
    float* d = slab + (rg * 8 + rr) * SLAB + eg * 8;
    *(float4*)(d + 0) = make_float4(acc[rr][0], acc[rr][1], acc[rr][2], acc[rr][3]);
    *(float4*)(d + 4) = make_float4(acc[rr][4], acc[rr][5], acc[rr][6], acc[rr][7]);
  }
  __syncthreads();

  // ---------------- epilogue: lane = row (64 rows per wave) ----------------
  float a[NEXP];
#pragma unroll
  for (int n = 0; n < NEXP; ++n) a[n] = slab[lane * SLAB + n];

  // top-8 by biased logits; strict > keeps lowest index on ties
  unsigned long long sel = 0ull;
  int idx[TOPK];
  float selu[TOPK];
#pragma unroll
  for (int k = 0; k < TOPK; ++k) {
    float best = -INFINITY, bestu = 0.f;
    int bi = 0;
#pragma unroll
    for (int n = 0; n < NEXP; ++n) {
      float vb = a[n] + bias[n];
      bool taken = (sel >> n) & 1ull;
      vb = taken ? -INFINITY : vb;
      if (vb > best) { best = vb; bestu = a[n]; bi = n; }
    }
    sel |= 1ull << bi;
    idx[k] = bi;
    selu[k] = bestu;
  }

  float mx = selu[0];
#pragma unroll
  for (int k = 1; k < TOPK; ++k) mx = fmaxf(mx, selu[k]);
  float g[TOPK]; float gs = 0.f;
#pragma unroll
  for (int k = 0; k < TOPK; ++k) { g[k] = __expf(selu[k] - mx); gs += g[k]; }
  float ginv = 1.f / gs;

  // gates: each lane writes its own row (16 float4 stores)
  float* grow = out + (wrow0 + lane) * NEXP;
#pragma unroll
  for (int n4 = 0; n4 < 16; ++n4) {
    float gv[4];
#pragma unroll
    for (int j = 0; j < 4; ++j) {
      int n = n4 * 4 + j;
      float v = 0.f;
#pragma unroll
      for (int k = 0; k < TOPK; ++k) v = (idx[k] == n) ? g[k] * ginv : v;
      gv[j] = v;
    }
    *(float4*)(grow + n4 * 4) = make_float4(gv[0], gv[1], gv[2], gv[3]);
  }

  // indices as float32 (2 float4 stores)
  float* irow = out + GOFF + (wrow0 + lane) * TOPK;
  *(float4*)(irow + 0) = make_float4((float)idx[0], (float)idx[1], (float)idx[2], (float)idx[3]);
  *(float4*)(irow + 4) = make_float4((float)idx[4], (float)idx[5], (float)idx[6], (float)idx[7]);

  // P_i softmax over all 64 logits; F_i via ballot
  float m2 = -INFINITY;
#pragma unroll
  for (int n = 0; n < NEXP; ++n) m2 = fmaxf(m2, a[n]);
  float s2 = 0.f;
#pragma unroll
  for (int n = 0; n < NEXP; ++n) s2 += __expf(a[n] - m2);
  float pinv = 1.f / s2;

  float myP = 0.f, myF = 0.f;
#pragma unroll
  for (int n = 0; n < NEXP; ++n) {
    float v = __expf(a[n] - m2) * pinv;
    v += __shfl_xor(v, 1);
    v += __shfl_xor(v, 2);
    v += __shfl_xor(v, 4);
    v += __shfl_xor(v, 8);
    v += __shfl_xor(v, 16);
    v += __shfl_xor(v, 32);
    unsigned long long b = __ballot((sel >> n) & 1ull);
    if (lane == n) { myP = v; myF = (float)__popcll(b); }
  }
  float* redF = lds + RED;
  float* redP = redF + 128;
  redF[w * 64 + lane] = myF;
  redP[w * 64 + lane] = myP;
  __syncthreads();
  if (tid < NEXP) {
    float F = redF[tid] + redF[64 + tid];
    float P = redP[tid] + redP[64 + tid];
    ws[(size_t)blockIdx.x * (2 * NEXP) + tid] = F;
    ws[(size_t)blockIdx.x * (2 * NEXP) + NEXP + tid] = P;
  }
}

// deterministic final reduction over the 512 block partials
__global__ __launch_bounds__(256) void router_aux(
    const float* __restrict__ ws, float* __restrict__ out)
{
  __shared__ float sf[4][NEXP];
  __shared__ float sp[4][NEXP];
  int t = threadIdx.x;
  int n = t & 63, part = t >> 6;
  float f = 0.f, p = 0.f;
#pragma unroll 8
  for (int b = part; b < NBLK; b += 4) {
    f += ws[(size_t)b * (2 * NEXP) + n];
    p += ws[(size_t)b * (2 * NEXP) + NEXP + n];
  }
  sf[part][n] = f;
  sp[part][n] = p;
  __syncthreads();
  if (t < NEXP) {
    float F = sf[0][t] + sf[1][t] + sf[2][t] + sf[3][t];
    float P = sp[0][t] + sp[1][t] + sp[2][t] + sp[3][t];
    float v = F * P;
    v += __shfl_xor(v, 1);
    v += __shfl_xor(v, 2);
    v += __shfl_xor(v, 4);
    v += __shfl_xor(v, 8);
    v += __shfl_xor(v, 16);
    v += __shfl_xor(v, 32);
    if (t == 0)
      out[AUX_OFF] = 0.01f * 64.f * v / (4294967296.0f /* 65536^2 */);
  }
}

extern "C" void kernel_launch(void* const* d_in, const int* in_sizes, int n_in,
                              void* d_out, int out_size, void* d_ws, size_t ws_size,
                              hipStream_t stream) {
  const float* x = (const float*)d_in[0];
  const float* W = (const float*)d_in[1];
  const float* bias = (const float*)d_in[2];
  float* out = (float*)d_out;
  float* ws = (float*)d_ws;
  router_main<<<NBLK, THREADS, 0, stream>>>(x, W, bias, out, ws);
  router_aux<<<1, 256, 0, stream>>>(ws, out);
}

// Round 7
// 803.436 us; speedup vs baseline: 1.6740x; 1.6740x over previous
//
#include <hip/hip_runtime.h>
#include <cstdint>
#include <cstddef>

#define B_ROWS 65536
#define DMODEL 2048
#define NEXP 64
#define TOPK 8
#define THREADS 256                    // 4 waves; each wave = 128 rows x D-slice 512
#define ROWS_PER_BLK 128
#define NBLK (B_ROWS / ROWS_PER_BLK)   // 512 blocks = 2 per CU
#define WSLICE (DMODEL / 4)            // 512
#define DC 16
#define NCH (WSLICE / DC)              // 32
#define XBUF 2048                      // floats per x buffer per wave (128 rows x 16)
#define SLAB 68
#define GOFF ((size_t)B_ROWS * NEXP)
#define AUX_OFF (GOFF + (size_t)B_ROWS * TOPK)

#define GLOAD16(g, l)                                                      \
  __builtin_amdgcn_global_load_lds(                                       \
      (const __attribute__((address_space(1))) void*)(g),                 \
      (__attribute__((address_space(3))) void*)(l), 16, 0, 0)

__global__ __launch_bounds__(THREADS, 2) void router_main(
    const float* __restrict__ x, const float* __restrict__ W,
    const float* __restrict__ bias, float* __restrict__ out,
    float* __restrict__ ws)
{
  // LDS union: loop = 4 waves x 2 bufs x 2048 floats (64KB, wave-private x).
  // epilogue = slab [128][68] (8704) + redF/redP (256) -- barrier-separated.
  __shared__ __align__(16) float lds[4 * 2 * XBUF];

  const int tid = threadIdx.x;
  const int lane = tid & 63;
  const int w = tid >> 6;          // wave = D-slice 0..3
  const int eg = lane & 7;         // expert group: experts eg*8..eg*8+7
  const int rg = lane >> 3;        // row group:    rows rg*16..rg*16+15
  const size_t row0 = (size_t)blockIdx.x * ROWS_PER_BLK;
  const int wd = w * WSLICE;

  float acc[16][8];
#pragma unroll
  for (int r = 0; r < 16; ++r)
#pragma unroll
    for (int e = 0; e < 8; ++e) acc[r][e] = 0.f;

  float* xbuf = lds + w * (2 * XBUF);

  // x staging: instr i covers rows i*16..i*16+15 (one rg). lane l -> row l>>2,
  // 16B col (l&3). Source col XOR'd by (i&1) so the read-side swizzle
  // (d4 ^ rg&1) lands on the right data; LDS dest stays LINEAR (gload_lds rule).
  const float* xg_e = x + (row0 + (size_t)(lane >> 2)) * DMODEL + wd + (lane & 3) * 4;
  const float* xg_o = x + (row0 + (size_t)(lane >> 2)) * DMODEL + wd + ((lane & 3) ^ 1) * 4;
  // W read direct from global (L2-resident, 8-way lane broadcast per instr)
  const float* Wg = W + (size_t)wd * NEXP + eg * 8;

#define STAGE(c, b)                                                        \
  do {                                                                     \
    float* dst_ = xbuf + (b) * XBUF;                                       \
    _Pragma("unroll") for (int i = 0; i < 8; ++i) {                        \
      const float* src_ = ((i & 1) ? xg_o : xg_e)                          \
                        + (size_t)i * 16 * DMODEL + (c) * DC;              \
      GLOAD16(src_, dst_ + i * 256);                                       \
    }                                                                      \
  } while (0)

#define FMA8(r, xs, wlo, whi)                                              \
  do {                                                                     \
    acc[r][0] = fmaf((xs), (wlo).x, acc[r][0]);                            \
    acc[r][1] = fmaf((xs), (wlo).y, acc[r][1]);                            \
    acc[r][2] = fmaf((xs), (wlo).z, acc[r][2]);                            \
    acc[r][3] = fmaf((xs), (wlo).w, acc[r][3]);                            \
    acc[r][4] = fmaf((xs), (whi).x, acc[r][4]);                            \
    acc[r][5] = fmaf((xs), (whi).y, acc[r][5]);                            \
    acc[r][6] = fmaf((xs), (whi).z, acc[r][6]);                            \
    acc[r][7] = fmaf((xs), (whi).w, acc[r][7]);                            \
  } while (0)

#define COMPUTE(c, b)                                                      \
  do {                                                                     \
    const float* xrd_ = xbuf + (b) * XBUF + rg * 256;                      \
    const float* wb_ = Wg + (size_t)(c) * (DC * NEXP);                     \
    _Pragma("unroll") for (int d4 = 0; d4 < 4; ++d4) {                     \
      float4 wlo0 = *(const float4*)(wb_ + (d4 * 4 + 0) * NEXP);           \
      float4 whi0 = *(const float4*)(wb_ + (d4 * 4 + 0) * NEXP + 4);       \
      float4 wlo1 = *(const float4*)(wb_ + (d4 * 4 + 1) * NEXP);           \
      float4 whi1 = *(const float4*)(wb_ + (d4 * 4 + 1) * NEXP + 4);       \
      float4 wlo2 = *(const float4*)(wb_ + (d4 * 4 + 2) * NEXP);           \
      float4 whi2 = *(const float4*)(wb_ + (d4 * 4 + 2) * NEXP + 4);       \
      float4 wlo3 = *(const float4*)(wb_ + (d4 * 4 + 3) * NEXP);           \
      float4 whi3 = *(const float4*)(wb_ + (d4 * 4 + 3) * NEXP + 4);       \
      const int xc_ = ((d4 ^ (rg & 1)) << 2);                              \
      _Pragma("unroll") for (int h = 0; h < 2; ++h) {                      \
        float4 xv[8];                                                      \
        _Pragma("unroll") for (int rr = 0; rr < 8; ++rr)                   \
          xv[rr] = *(const float4*)(xrd_ + (h * 8 + rr) * 16 + xc_);       \
        _Pragma("unroll") for (int rr = 0; rr < 8; ++rr) {                 \
          FMA8(h * 8 + rr, xv[rr].x, wlo0, whi0);                          \
          FMA8(h * 8 + rr, xv[rr].y, wlo1, whi1);                          \
          FMA8(h * 8 + rr, xv[rr].z, wlo2, whi2);                          \
          FMA8(h * 8 + rr, xv[rr].w, wlo3, whi3);                          \
        }                                                                  \
      }                                                                    \
    }                                                                      \
  } while (0)

  STAGE(0, 0);
  for (int c = 0; c < NCH; ++c) {
    __syncthreads();                    // stage(c) visible; buf ((c+1)&1) free
    if (c + 1 < NCH) STAGE(c + 1, (c + 1) & 1);
    COMPUTE(c, c & 1);
  }
  __syncthreads();   // all compute done; staging area dies, slab becomes live

  // ---- combine the 4 D-slice partials: sequential rounds (deterministic) ----
  float* slab = lds;   // [128][SLAB]
#pragma unroll
  for (int pp = 0; pp < 4; ++pp) {
    if (w == pp) {
#pragma unroll
      for (int rr = 0; rr < 16; ++rr) {
        float* d = slab + (rg * 16 + rr) * SLAB + eg * 8;
        if (pp == 0) {
          *(float4*)(d + 0) = make_float4(acc[rr][0], acc[rr][1], acc[rr][2], acc[rr][3]);
          *(float4*)(d + 4) = make_float4(acc[rr][4], acc[rr][5], acc[rr][6], acc[rr][7]);
        } else {
          float4 lo = *(const float4*)(d + 0), hi = *(const float4*)(d + 4);
          lo.x += acc[rr][0]; lo.y += acc[rr][1]; lo.z += acc[rr][2]; lo.w += acc[rr][3];
          hi.x += acc[rr][4]; hi.y += acc[rr][5]; hi.z += acc[rr][6]; hi.w += acc[rr][7];
          *(float4*)(d + 0) = lo; *(float4*)(d + 4) = hi;
        }
      }
    }
    __syncthreads();
  }

  // ---------------- epilogue: waves 0-1, lane = row ----------------
  float* redF = lds + 128 * SLAB;       // 128 floats
  float* redP = redF + 128;             // 128 floats

  if (w < 2) {
    const int row = w * 64 + lane;
    float a[NEXP];
#pragma unroll
    for (int n = 0; n < NEXP; ++n) a[n] = slab[row * SLAB + n];

    // top-8 by biased logits; strict > keeps lowest index on ties
    unsigned long long sel = 0ull;
    int idx[TOPK];
    float selu[TOPK];
#pragma unroll
    for (int k = 0; k < TOPK; ++k) {
      float best = -INFINITY, bestu = 0.f;
      int bi = 0;
#pragma unroll
      for (int n = 0; n < NEXP; ++n) {
        float vb = a[n] + bias[n];
        bool taken = (sel >> n) & 1ull;
        vb = taken ? -INFINITY : vb;
        if (vb > best) { best = vb; bestu = a[n]; bi = n; }
      }
      sel |= 1ull << bi;
      idx[k] = bi;
      selu[k] = bestu;
    }

    float mx = selu[0];
#pragma unroll
    for (int k = 1; k < TOPK; ++k) mx = fmaxf(mx, selu[k]);
    float g[TOPK]; float gs = 0.f;
#pragma unroll
    for (int k = 0; k < TOPK; ++k) { g[k] = __expf(selu[k] - mx); gs += g[k]; }
    float ginv = 1.f / gs;

    // gates: each lane writes its own row (16 float4 stores)
    float* grow = out + (row0 + row) * NEXP;
#pragma unroll
    for (int n4 = 0; n4 < 16; ++n4) {
      float gv[4];
#pragma unroll
      for (int j = 0; j < 4; ++j) {
        int n = n4 * 4 + j;
        float v = 0.f;
#pragma unroll
        for (int k = 0; k < TOPK; ++k) v = (idx[k] == n) ? g[k] * ginv : v;
        gv[j] = v;
      }
      *(float4*)(grow + n4 * 4) = make_float4(gv[0], gv[1], gv[2], gv[3]);
    }

    // indices as float32
    float* irow = out + GOFF + (row0 + row) * TOPK;
    *(float4*)(irow + 0) = make_float4((float)idx[0], (float)idx[1], (float)idx[2], (float)idx[3]);
    *(float4*)(irow + 4) = make_float4((float)idx[4], (float)idx[5], (float)idx[6], (float)idx[7]);

    // P_i softmax over all 64 logits; F_i via ballot
    float m2 = -INFINITY;
#pragma unroll
    for (int n = 0; n < NEXP; ++n) m2 = fmaxf(m2, a[n]);
    float s2 = 0.f;
#pragma unroll
    for (int n = 0; n < NEXP; ++n) s2 += __expf(a[n] - m2);
    float pinv = 1.f / s2;

    float myP = 0.f, myF = 0.f;
#pragma unroll
    for (int n = 0; n < NEXP; ++n) {
      float v = __expf(a[n] - m2) * pinv;
      v += __shfl_xor(v, 1);
      v += __shfl_xor(v, 2);
      v += __shfl_xor(v, 4);
      v += __shfl_xor(v, 8);
      v += __shfl_xor(v, 16);
      v += __shfl_xor(v, 32);
      unsigned long long b = __ballot((sel >> n) & 1ull);
      if (lane == n) { myP = v; myF = (float)__popcll(b); }
    }
    redF[w * 64 + lane] = myF;
    redP[w * 64 + lane] = myP;
  }

  __syncthreads();
  if (tid < NEXP) {
    float F = redF[tid] + redF[64 + tid];
    float P = redP[tid] + redP[64 + tid];
    ws[(size_t)blockIdx.x * (2 * NEXP) + tid] = F;
    ws[(size_t)blockIdx.x * (2 * NEXP) + NEXP + tid] = P;
  }
}

// deterministic final reduction over the 512 block partials
__global__ __launch_bounds__(256) void router_aux(
    const float* __restrict__ ws, float* __restrict__ out)
{
  __shared__ float sf[4][NEXP];
  __shared__ float sp[4][NEXP];
  int t = threadIdx.x;
  int n = t & 63, part = t >> 6;
  float f = 0.f, p = 0.f;
#pragma unroll 8
  for (int b = part; b < NBLK; b += 4) {
    f += ws[(size_t)b * (2 * NEXP) + n];
    p += ws[(size_t)b * (2 * NEXP) + NEXP + n];
  }
  sf[part][n] = f;
  sp[part][n] = p;
  __syncthreads();
  if (t < NEXP) {
    float F = sf[0][t] + sf[1][t] + sf[2][t] + sf[3][t];
    float P = sp[0][t] + sp[1][t] + sp[2][t] + sp[3][t];
    float v = F * P;
    v += __shfl_xor(v, 1);
    v += __shfl_xor(v, 2);
    v += __shfl_xor(v, 4);
    v += __shfl_xor(v, 8);
    v += __shfl_xor(v, 16);
    v += __shfl_xor(v, 32);
    if (t == 0)
      out[AUX_OFF] = 0.01f * 64.f * v / (4294967296.0f /* 65536^2 */);
  }
}

extern "C" void kernel_launch(void* const* d_in, const int* in_sizes, int n_in,
                              void* d_out, int out_size, void* d_ws, size_t ws_size,
                              hipStream_t stream) {
  const float* x = (const float*)d_in[0];
  const float* W = (const float*)d_in[1];
  const float* bias = (const float*)d_in[2];
  float* out = (float*)d_out;
  float* ws = (float*)d_ws;
  router_main<<<NBLK, THREADS, 0, stream>>>(x, W, bias, out, ws);
  router_aux<<<1, 256, 0, stream>>>(ws, out);
}

// Round 8
// 212.836 us; speedup vs baseline: 6.3190x; 3.7749x over previous
//
#include <hip/hip_runtime.h>
#include <cstdint>
#include <cstddef>

typedef __attribute__((ext_vector_type(8))) short short8;
typedef __attribute__((ext_vector_type(4))) float f32x4;

#define B_ROWS 65536
#define DMODEL 2048
#define NEXP 64
#define TOPK 8
#define THREADS 256                      // 4 waves; wave = 32 rows x 64 experts
#define ROWS_PER_BLK 128
#define NBLK (B_ROWS / ROWS_PER_BLK)     // 512 blocks = 2 per CU
#define NKS (DMODEL / 32)                // 64 k-steps
#define SLAB 72
#define GOFF ((size_t)B_ROWS * NEXP)
#define AUX_OFF (GOFF + (size_t)B_ROWS * TOPK)
#define WS_FRAG_OFF 65536                // float offset of W-frag region in ws

__device__ __forceinline__ unsigned short bf16_rne(float v, float* back) {
  unsigned u = __float_as_uint(v);
  unsigned r = (u + 0x7FFFu + ((u >> 16) & 1u)) >> 16;
  *back = __uint_as_float(r << 16);
  return (unsigned short)r;
}

// W -> bf16x3 B-fragments, lane-ordered for mfma_f32_16x16x32_bf16.
// frag[(ks*4+nt)*3 + t] is a 512-bf16 (1KB) fragment: lane l holds 8 contig
// bf16 at l*8: B[k = ks*32 + (l>>4)*8 + j][col = nt*16 + (l&15)], term t.
__global__ __launch_bounds__(256) void router_prep(
    const float* __restrict__ W, unsigned short* __restrict__ frag)
{
  const int ks = blockIdx.x;             // 0..63
  const int tid = threadIdx.x;
  const int nt = tid >> 6;
  const int lane = tid & 63;
  const int krow = ks * 32 + (lane >> 4) * 8;
  const int col = nt * 16 + (lane & 15);
  short8 hv, mv, lv;
#pragma unroll
  for (int j = 0; j < 8; ++j) {
    float v = W[(size_t)(krow + j) * NEXP + col];
    float fh, fm, fl;
    unsigned short h = bf16_rne(v, &fh);
    float r = v - fh;
    unsigned short m = bf16_rne(r, &fm);
    float r2 = r - fm;
    unsigned short l = bf16_rne(r2, &fl);
    hv[j] = (short)h; mv[j] = (short)m; lv[j] = (short)l;
  }
  size_t base = (size_t)(ks * 4 + nt) * 3 * 512 + lane * 8;
  *(short8*)(frag + base)        = hv;
  *(short8*)(frag + base + 512)  = mv;
  *(short8*)(frag + base + 1024) = lv;
}

__device__ __forceinline__ void cvt3(float4 a, float4 b,
                                     short8* H, short8* M, short8* L) {
  float f[8] = {a.x, a.y, a.z, a.w, b.x, b.y, b.z, b.w};
#pragma unroll
  for (int j = 0; j < 8; ++j) {
    float fh, fm, fl;
    unsigned short h = bf16_rne(f[j], &fh);
    float r = f[j] - fh;
    unsigned short m = bf16_rne(r, &fm);
    float r2 = r - fm;
    unsigned short l = bf16_rne(r2, &fl);
    (*H)[j] = (short)h; (*M)[j] = (short)m; (*L)[j] = (short)l;
  }
}

#define MFMA __builtin_amdgcn_mfma_f32_16x16x32_bf16

__global__ __launch_bounds__(THREADS, 2) void router_main(
    const float* __restrict__ x, const float* __restrict__ bias,
    const unsigned short* __restrict__ frag, float* __restrict__ out,
    float* __restrict__ ws)
{
  __shared__ __align__(16) float lds[ROWS_PER_BLK * SLAB + 256];

  const int tid = threadIdx.x;
  const int lane = tid & 63;
  const int w = tid >> 6;
  const size_t row0 = (size_t)blockIdx.x * ROWS_PER_BLK;

  f32x4 acc[2][4];
#pragma unroll
  for (int m = 0; m < 2; ++m)
#pragma unroll
    for (int nt = 0; nt < 4; ++nt) acc[m][nt] = (f32x4){0.f, 0.f, 0.f, 0.f};

  // A-side source: lane l -> row (l&15), k-cols (l>>4)*8 .. +7
  const float* xp0 = x + (row0 + (size_t)w * 32 + (lane & 15)) * DMODEL
                   + (lane >> 4) * 8;
  const float* xp1 = xp0 + (size_t)16 * DMODEL;
  const short8* fb = (const short8*)frag;   // fragment = 64 short8 per 1KB

  for (int ks = 0; ks < NKS; ++ks) {
    // x tiles (global; 16 rows x 128B contiguous per m-tile across 2 instrs)
    float4 a00 = *(const float4*)(xp0 + ks * 32);
    float4 a01 = *(const float4*)(xp0 + ks * 32 + 4);
    float4 a10 = *(const float4*)(xp1 + ks * 32);
    float4 a11 = *(const float4*)(xp1 + ks * 32 + 4);
    // B fragments (L2-resident, 1KB coalesced per load)
    short8 Bh[4], Bm[4], Bl[4];
#pragma unroll
    for (int nt = 0; nt < 4; ++nt) {
      size_t fb0 = (size_t)(ks * 4 + nt) * 3 * 64 + lane;
      Bh[nt] = fb[fb0];
      Bm[nt] = fb[fb0 + 64];
      Bl[nt] = fb[fb0 + 128];
    }
    short8 Ah0, Am0, Al0, Ah1, Am1, Al1;
    cvt3(a00, a01, &Ah0, &Am0, &Al0);
    cvt3(a10, a11, &Ah1, &Am1, &Al1);
#pragma unroll
    for (int nt = 0; nt < 4; ++nt) {
      acc[0][nt] = MFMA(Ah0, Bh[nt], acc[0][nt], 0, 0, 0);
      acc[0][nt] = MFMA(Ah0, Bm[nt], acc[0][nt], 0, 0, 0);
      acc[0][nt] = MFMA(Am0, Bh[nt], acc[0][nt], 0, 0, 0);
      acc[0][nt] = MFMA(Am0, Bm[nt], acc[0][nt], 0, 0, 0);
      acc[0][nt] = MFMA(Ah0, Bl[nt], acc[0][nt], 0, 0, 0);
      acc[0][nt] = MFMA(Al0, Bh[nt], acc[0][nt], 0, 0, 0);
      acc[1][nt] = MFMA(Ah1, Bh[nt], acc[1][nt], 0, 0, 0);
      acc[1][nt] = MFMA(Ah1, Bm[nt], acc[1][nt], 0, 0, 0);
      acc[1][nt] = MFMA(Am1, Bh[nt], acc[1][nt], 0, 0, 0);
      acc[1][nt] = MFMA(Am1, Bm[nt], acc[1][nt], 0, 0, 0);
      acc[1][nt] = MFMA(Ah1, Bl[nt], acc[1][nt], 0, 0, 0);
      acc[1][nt] = MFMA(Al1, Bh[nt], acc[1][nt], 0, 0, 0);
    }
  }

  // D-frag -> slab[row][expert]: col = lane&15, row = (lane>>4)*4 + reg
  float* slab = lds;
#pragma unroll
  for (int m = 0; m < 2; ++m)
#pragma unroll
    for (int nt = 0; nt < 4; ++nt)
#pragma unroll
      for (int reg = 0; reg < 4; ++reg) {
        int row = w * 32 + m * 16 + (lane >> 4) * 4 + reg;
        int col = nt * 16 + (lane & 15);
        slab[row * SLAB + col] = acc[m][nt][reg];
      }
  __syncthreads();

  // ---------------- epilogue: waves 0-1, lane = row ----------------
  float* redF = lds + ROWS_PER_BLK * SLAB;   // 128 floats
  float* redP = redF + 128;                  // 128 floats

  if (w < 2) {
    const int row = w * 64 + lane;
    float a[NEXP];
#pragma unroll
    for (int n = 0; n < NEXP; ++n) a[n] = slab[row * SLAB + n];

    // top-8 by biased logits; strict > keeps lowest index on ties
    unsigned long long sel = 0ull;
    int idx[TOPK];
    float selu[TOPK];
#pragma unroll
    for (int k = 0; k < TOPK; ++k) {
      float best = -INFINITY, bestu = 0.f;
      int bi = 0;
#pragma unroll
      for (int n = 0; n < NEXP; ++n) {
        float vb = a[n] + bias[n];
        bool taken = (sel >> n) & 1ull;
        vb = taken ? -INFINITY : vb;
        if (vb > best) { best = vb; bestu = a[n]; bi = n; }
      }
      sel |= 1ull << bi;
      idx[k] = bi;
      selu[k] = bestu;
    }

    float mx = selu[0];
#pragma unroll
    for (int k = 1; k < TOPK; ++k) mx = fmaxf(mx, selu[k]);
    float g[TOPK]; float gs = 0.f;
#pragma unroll
    for (int k = 0; k < TOPK; ++k) { g[k] = __expf(selu[k] - mx); gs += g[k]; }
    float ginv = 1.f / gs;

    float* grow = out + (row0 + row) * NEXP;
#pragma unroll
    for (int n4 = 0; n4 < 16; ++n4) {
      float gv[4];
#pragma unroll
      for (int j = 0; j < 4; ++j) {
        int n = n4 * 4 + j;
        float v = 0.f;
#pragma unroll
        for (int k = 0; k < TOPK; ++k) v = (idx[k] == n) ? g[k] * ginv : v;
        gv[j] = v;
      }
      *(float4*)(grow + n4 * 4) = make_float4(gv[0], gv[1], gv[2], gv[3]);
    }

    float* irow = out + GOFF + (row0 + row) * TOPK;
    *(float4*)(irow + 0) = make_float4((float)idx[0], (float)idx[1], (float)idx[2], (float)idx[3]);
    *(float4*)(irow + 4) = make_float4((float)idx[4], (float)idx[5], (float)idx[6], (float)idx[7]);

    float m2 = -INFINITY;
#pragma unroll
    for (int n = 0; n < NEXP; ++n) m2 = fmaxf(m2, a[n]);
    float s2 = 0.f;
#pragma unroll
    for (int n = 0; n < NEXP; ++n) s2 += __expf(a[n] - m2);
    float pinv = 1.f / s2;

    float myP = 0.f, myF = 0.f;
#pragma unroll
    for (int n = 0; n < NEXP; ++n) {
      float v = __expf(a[n] - m2) * pinv;
      v += __shfl_xor(v, 1);
      v += __shfl_xor(v, 2);
      v += __shfl_xor(v, 4);
      v += __shfl_xor(v, 8);
      v += __shfl_xor(v, 16);
      v += __shfl_xor(v, 32);
      unsigned long long b = __ballot((sel >> n) & 1ull);
      if (lane == n) { myP = v; myF = (float)__popcll(b); }
    }
    redF[w * 64 + lane] = myF;
    redP[w * 64 + lane] = myP;
  }

  __syncthreads();
  if (tid < NEXP) {
    float F = redF[tid] + redF[64 + tid];
    float P = redP[tid] + redP[64 + tid];
    ws[(size_t)blockIdx.x * (2 * NEXP) + tid] = F;
    ws[(size_t)blockIdx.x * (2 * NEXP) + NEXP + tid] = P;
  }
}

// deterministic final reduction over the 512 block partials
__global__ __launch_bounds__(256) void router_aux(
    const float* __restrict__ ws, float* __restrict__ out)
{
  __shared__ float sf[4][NEXP];
  __shared__ float sp[4][NEXP];
  int t = threadIdx.x;
  int n = t & 63, part = t >> 6;
  float f = 0.f, p = 0.f;
#pragma unroll 8
  for (int b = part; b < NBLK; b += 4) {
    f += ws[(size_t)b * (2 * NEXP) + n];
    p += ws[(size_t)b * (2 * NEXP) + NEXP + n];
  }
  sf[part][n] = f;
  sp[part][n] = p;
  __syncthreads();
  if (t < NEXP) {
    float F = sf[0][t] + sf[1][t] + sf[2][t] + sf[3][t];
    float P = sp[0][t] + sp[1][t] + sp[2][t] + sp[3][t];
    float v = F * P;
    v += __shfl_xor(v, 1);
    v += __shfl_xor(v, 2);
    v += __shfl_xor(v, 4);
    v += __shfl_xor(v, 8);
    v += __shfl_xor(v, 16);
    v += __shfl_xor(v, 32);
    if (t == 0)
      out[AUX_OFF] = 0.01f * 64.f * v / (4294967296.0f /* 65536^2 */);
  }
}

extern "C" void kernel_launch(void* const* d_in, const int* in_sizes, int n_in,
                              void* d_out, int out_size, void* d_ws, size_t ws_size,
                              hipStream_t stream) {
  const float* x = (const float*)d_in[0];
  const float* W = (const float*)d_in[1];
  const float* bias = (const float*)d_in[2];
  float* out = (float*)d_out;
  float* ws = (float*)d_ws;
  unsigned short* frag = (unsigned short*)(ws + WS_FRAG_OFF);
  router_prep<<<NKS, 256, 0, stream>>>(W, frag);
  router_main<<<NBLK, THREADS, 0, stream>>>(x, bias, frag, out, ws);
  router_aux<<<1, 256, 0, stream>>>(ws, out);
}

// Round 9
// 209.688 us; speedup vs baseline: 6.4139x; 1.0150x over previous
//
#include <hip/hip_runtime.h>
#include <cstdint>
#include <cstddef>

typedef __attribute__((ext_vector_type(8))) short short8;
typedef __attribute__((ext_vector_type(4))) float f32x4;

#define B_ROWS 65536
#define DMODEL 2048
#define NEXP 64
#define TOPK 8
#define THREADS 256                      // 4 waves; wave = 32 rows x 64 experts
#define ROWS_PER_BLK 128
#define NBLK (B_ROWS / ROWS_PER_BLK)     // 512 blocks = 2 per CU
#define NKS (DMODEL / 32)                // 64 k-steps
#define SLAB 72
#define GOFF ((size_t)B_ROWS * NEXP)
#define AUX_OFF (GOFF + (size_t)B_ROWS * TOPK)
#define WS_FRAG_OFF 65536                // float offset of W-frag region in ws

__device__ __forceinline__ unsigned short bf16_rne(float v, float* back) {
  unsigned u = __float_as_uint(v);
  unsigned r = (u + 0x7FFFu + ((u >> 16) & 1u)) >> 16;
  *back = __uint_as_float(r << 16);
  return (unsigned short)r;
}

// W -> bf16x3 B-fragments, lane-ordered for mfma_f32_16x16x32_bf16.
// frag[(ks*4+nt)*3 + t] is a 512-bf16 (1KB) fragment: lane l holds 8 contig
// bf16 at l*8: B[k = ks*32 + (l>>4)*8 + j][col = nt*16 + (l&15)], term t.
__global__ __launch_bounds__(256) void router_prep(
    const float* __restrict__ W, unsigned short* __restrict__ frag)
{
  const int ks = blockIdx.x;             // 0..63
  const int tid = threadIdx.x;
  const int nt = tid >> 6;
  const int lane = tid & 63;
  const int krow = ks * 32 + (lane >> 4) * 8;
  const int col = nt * 16 + (lane & 15);
  short8 hv, mv, lv;
#pragma unroll
  for (int j = 0; j < 8; ++j) {
    float v = W[(size_t)(krow + j) * NEXP + col];
    float fh, fm, fl;
    unsigned short h = bf16_rne(v, &fh);
    float r = v - fh;
    unsigned short m = bf16_rne(r, &fm);
    float r2 = r - fm;
    unsigned short l = bf16_rne(r2, &fl);
    hv[j] = (short)h; mv[j] = (short)m; lv[j] = (short)l;
  }
  size_t base = (size_t)(ks * 4 + nt) * 3 * 512 + lane * 8;
  *(short8*)(frag + base)        = hv;
  *(short8*)(frag + base + 512)  = mv;
  *(short8*)(frag + base + 1024) = lv;
}

__device__ __forceinline__ void cvt3(float4 a, float4 b,
                                     short8* H, short8* M, short8* L) {
  float f[8] = {a.x, a.y, a.z, a.w, b.x, b.y, b.z, b.w};
#pragma unroll
  for (int j = 0; j < 8; ++j) {
    float fh, fm, fl;
    unsigned short h = bf16_rne(f[j], &fh);
    float r = f[j] - fh;
    unsigned short m = bf16_rne(r, &fm);
    float r2 = r - fm;
    unsigned short l = bf16_rne(r2, &fl);
    (*H)[j] = (short)h; (*M)[j] = (short)m; (*L)[j] = (short)l;
  }
}

#define MFMA __builtin_amdgcn_mfma_f32_16x16x32_bf16

__global__ __launch_bounds__(THREADS, 2) void router_main(
    const float* __restrict__ x, const float* __restrict__ bias,
    const unsigned short* __restrict__ frag, float* __restrict__ out,
    float* __restrict__ ws)
{
  __shared__ __align__(16) float lds[ROWS_PER_BLK * SLAB + 256];

  const int tid = threadIdx.x;
  const int lane = tid & 63;
  const int w = tid >> 6;
  const size_t row0 = (size_t)blockIdx.x * ROWS_PER_BLK;

  f32x4 acc[2][4];
#pragma unroll
  for (int m = 0; m < 2; ++m)
#pragma unroll
    for (int nt = 0; nt < 4; ++nt) acc[m][nt] = (f32x4){0.f, 0.f, 0.f, 0.f};

  // A-side source: lane l -> row (l&15), k-cols (l>>4)*8 .. +7
  const float* xp0 = x + (row0 + (size_t)w * 32 + (lane & 15)) * DMODEL
                   + (lane >> 4) * 8;
  const float* xp1 = xp0 + (size_t)16 * DMODEL;
  const short8* fb = (const short8*)frag;   // fragment = 64 short8 per 1KB

  // B-fragment load (short8 units): (ks*4+nt)*3*64 + lane, terms at +0/+64/+128
#define LOAD_B(KS, NT, BH, BM, BL)                                         \
  do {                                                                     \
    size_t fb0_ = (size_t)((KS) * 4 + (NT)) * 3 * 64 + lane;               \
    BH = fb[fb0_]; BM = fb[fb0_ + 64]; BL = fb[fb0_ + 128];                \
  } while (0)

#define MFMA12(NT, BH, BM, BL)                                             \
  do {                                                                     \
    acc[0][NT] = MFMA(Ah0, BH, acc[0][NT], 0, 0, 0);                       \
    acc[0][NT] = MFMA(Ah0, BM, acc[0][NT], 0, 0, 0);                       \
    acc[0][NT] = MFMA(Am0, BH, acc[0][NT], 0, 0, 0);                       \
    acc[0][NT] = MFMA(Am0, BM, acc[0][NT], 0, 0, 0);                       \
    acc[0][NT] = MFMA(Ah0, BL, acc[0][NT], 0, 0, 0);                       \
    acc[0][NT] = MFMA(Al0, BH, acc[0][NT], 0, 0, 0);                       \
    acc[1][NT] = MFMA(Ah1, BH, acc[1][NT], 0, 0, 0);                       \
    acc[1][NT] = MFMA(Ah1, BM, acc[1][NT], 0, 0, 0);                       \
    acc[1][NT] = MFMA(Am1, BH, acc[1][NT], 0, 0, 0);                       \
    acc[1][NT] = MFMA(Am1, BM, acc[1][NT], 0, 0, 0);                       \
    acc[1][NT] = MFMA(Ah1, BL, acc[1][NT], 0, 0, 0);                       \
    acc[1][NT] = MFMA(Al1, BH, acc[1][NT], 0, 0, 0);                       \
  } while (0)

  // k-step body: x(ks) already in c00..c11; optionally prefetch x(ks+1).
#define KSTEP(KS, PREF)                                                    \
  do {                                                                     \
    float4 n00, n01, n10, n11;                                             \
    if (PREF) {                        /* issue next x loads first */      \
      n00 = *(const float4*)(xp0 + ((KS) + 1) * 32);                       \
      n01 = *(const float4*)(xp0 + ((KS) + 1) * 32 + 4);                   \
      n10 = *(const float4*)(xp1 + ((KS) + 1) * 32);                       \
      n11 = *(const float4*)(xp1 + ((KS) + 1) * 32 + 4);                   \
    }                                                                      \
    LOAD_B(KS, 0, BhA, BmA, BlA);                                          \
    short8 Ah0, Am0, Al0, Ah1, Am1, Al1;                                   \
    cvt3(c00, c01, &Ah0, &Am0, &Al0);                                      \
    cvt3(c10, c11, &Ah1, &Am1, &Al1);                                      \
    LOAD_B(KS, 1, BhB, BmB, BlB);                                          \
    MFMA12(0, BhA, BmA, BlA);                                              \
    LOAD_B(KS, 2, BhA, BmA, BlA);                                          \
    MFMA12(1, BhB, BmB, BlB);                                              \
    LOAD_B(KS, 3, BhB, BmB, BlB);                                          \
    MFMA12(2, BhA, BmA, BlA);                                              \
    MFMA12(3, BhB, BmB, BlB);                                              \
    if (PREF) { c00 = n00; c01 = n01; c10 = n10; c11 = n11; }              \
  } while (0)

  float4 c00 = *(const float4*)(xp0);
  float4 c01 = *(const float4*)(xp0 + 4);
  float4 c10 = *(const float4*)(xp1);
  float4 c11 = *(const float4*)(xp1 + 4);
  short8 BhA, BmA, BlA, BhB, BmB, BlB;

  for (int ks = 0; ks < NKS - 1; ++ks) KSTEP(ks, 1);
  KSTEP(NKS - 1, 0);

  // D-frag -> slab[row][expert]: col = lane&15, row = (lane>>4)*4 + reg
  float* slab = lds;
#pragma unroll
  for (int m = 0; m < 2; ++m)
#pragma unroll
    for (int nt = 0; nt < 4; ++nt)
#pragma unroll
      for (int reg = 0; reg < 4; ++reg) {
        int row = w * 32 + m * 16 + (lane >> 4) * 4 + reg;
        int col = nt * 16 + (lane & 15);
        slab[row * SLAB + col] = acc[m][nt][reg];
      }
  __syncthreads();

  // ---------------- epilogue: waves 0-1, lane = row ----------------
  float* redF = lds + ROWS_PER_BLK * SLAB;   // 128 floats
  float* redP = redF + 128;                  // 128 floats

  if (w < 2) {
    const int row = w * 64 + lane;
    float a[NEXP];
#pragma unroll
    for (int n = 0; n < NEXP; ++n) a[n] = slab[row * SLAB + n];

    // top-8 by biased logits; strict > keeps lowest index on ties
    unsigned long long sel = 0ull;
    int idx[TOPK];
    float selu[TOPK];
#pragma unroll
    for (int k = 0; k < TOPK; ++k) {
      float best = -INFINITY, bestu = 0.f;
      int bi = 0;
#pragma unroll
      for (int n = 0; n < NEXP; ++n) {
        float vb = a[n] + bias[n];
        bool taken = (sel >> n) & 1ull;
        vb = taken ? -INFINITY : vb;
        if (vb > best) { best = vb; bestu = a[n]; bi = n; }
      }
      sel |= 1ull << bi;
      idx[k] = bi;
      selu[k] = bestu;
    }

    float mx = selu[0];
#pragma unroll
    for (int k = 1; k < TOPK; ++k) mx = fmaxf(mx, selu[k]);
    float g[TOPK]; float gs = 0.f;
#pragma unroll
    for (int k = 0; k < TOPK; ++k) { g[k] = __expf(selu[k] - mx); gs += g[k]; }
    float ginv = 1.f / gs;

    float* grow = out + (row0 + row) * NEXP;
#pragma unroll
    for (int n4 = 0; n4 < 16; ++n4) {
      float gv[4];
#pragma unroll
      for (int j = 0; j < 4; ++j) {
        int n = n4 * 4 + j;
        float v = 0.f;
#pragma unroll
        for (int k = 0; k < TOPK; ++k) v = (idx[k] == n) ? g[k] * ginv : v;
        gv[j] = v;
      }
      *(float4*)(grow + n4 * 4) = make_float4(gv[0], gv[1], gv[2], gv[3]);
    }

    float* irow = out + GOFF + (row0 + row) * TOPK;
    *(float4*)(irow + 0) = make_float4((float)idx[0], (float)idx[1], (float)idx[2], (float)idx[3]);
    *(float4*)(irow + 4) = make_float4((float)idx[4], (float)idx[5], (float)idx[6], (float)idx[7]);

    float m2 = -INFINITY;
#pragma unroll
    for (int n = 0; n < NEXP; ++n) m2 = fmaxf(m2, a[n]);
    float s2 = 0.f;
#pragma unroll
    for (int n = 0; n < NEXP; ++n) s2 += __expf(a[n] - m2);
    float pinv = 1.f / s2;

    float myP = 0.f, myF = 0.f;
#pragma unroll
    for (int n = 0; n < NEXP; ++n) {
      float v = __expf(a[n] - m2) * pinv;
      v += __shfl_xor(v, 1);
      v += __shfl_xor(v, 2);
      v += __shfl_xor(v, 4);
      v += __shfl_xor(v, 8);
      v += __shfl_xor(v, 16);
      v += __shfl_xor(v, 32);
      unsigned long long b = __ballot((sel >> n) & 1ull);
      if (lane == n) { myP = v; myF = (float)__popcll(b); }
    }
    redF[w * 64 + lane] = myF;
    redP[w * 64 + lane] = myP;
  }

  __syncthreads();
  if (tid < NEXP) {
    float F = redF[tid] + redF[64 + tid];
    float P = redP[tid] + redP[64 + tid];
    ws[(size_t)blockIdx.x * (2 * NEXP) + tid] = F;
    ws[(size_t)blockIdx.x * (2 * NEXP) + NEXP + tid] = P;
  }
}

// deterministic final reduction over the 512 block partials
__global__ __launch_bounds__(256) void router_aux(
    const float* __restrict__ ws, float* __restrict__ out)
{
  __shared__ float sf[4][NEXP];
  __shared__ float sp[4][NEXP];
  int t = threadIdx.x;
  int n = t & 63, part = t >> 6;
  float f = 0.f, p = 0.f;
#pragma unroll 8
  for (int b = part; b < NBLK; b += 4) {
    f += ws[(size_t)b * (2 * NEXP) + n];
    p += ws[(size_t)b * (2 * NEXP) + NEXP + n];
  }
  sf[part][n] = f;
  sp[part][n] = p;
  __syncthreads();
  if (t < NEXP) {
    float F = sf[0][t] + sf[1][t] + sf[2][t] + sf[3][t];
    float P = sp[0][t] + sp[1][t] + sp[2][t] + sp[3][t];
    float v = F * P;
    v += __shfl_xor(v, 1);
    v += __shfl_xor(v, 2);
    v += __shfl_xor(v, 4);
    v += __shfl_xor(v, 8);
    v += __shfl_xor(v, 16);
    v += __shfl_xor(v, 32);
    if (t == 0)
      out[AUX_OFF] = 0.01f * 64.f * v / (4294967296.0f /* 65536^2 */);
  }
}

extern "C" void kernel_launch(void* const* d_in, const int* in_sizes, int n_in,
                              void* d_out, int out_size, void* d_ws, size_t ws_size,
                              hipStream_t stream) {
  const float* x = (const float*)d_in[0];
  const float* W = (const float*)d_in[1];
  const float* bias = (const float*)d_in[2];
  float* out = (float*)d_out;
  float* ws = (float*)d_ws;
  unsigned short* frag = (unsigned short*)(ws + WS_FRAG_OFF);
  router_prep<<<NKS, 256, 0, stream>>>(W, frag);
  router_main<<<NBLK, THREADS, 0, stream>>>(x, bias, frag, out, ws);
  router_aux<<<1, 256, 0, stream>>>(ws, out);
}